// Round 7
// baseline (168.374 us; speedup 1.0000x reference)
//
#include <hip/hip_runtime.h>
#include <hip/hip_fp16.h>
#include <stdint.h>

// out[16384,1024] = fp16(x) @ (fp16(sparsify24(fp16(W))) * scale -> fp16) + bias
#define M_TOT 16384
#define N_TOT 1024
#define K_TOT 1024

typedef _Float16 f16x8 __attribute__((ext_vector_type(8)));
typedef float f32x4 __attribute__((ext_vector_type(4)));
typedef unsigned short ushort4v __attribute__((ext_vector_type(4)));

// async global->LDS DMA, 16B per lane. LDS dest must be wave-uniform base + lane*16.
__device__ inline void gl2lds16(const void* g, void* l) {
    __builtin_amdgcn_global_load_lds(
        (const __attribute__((address_space(1))) void*)(uintptr_t)(g),
        (__attribute__((address_space(3))) void*)(uint32_t)(uintptr_t)(l),
        16, 0, 0);
}

// --- Kernel 1: weight prep only. The x fp32->fp16 cast is fused into the GEMM's
// A-staging, deleting a 96 MB HBM round-trip (64 MB X read + 32 MB xh write) and
// one-kernel's worth of serialized time.
// W[K][N] fp32 -> fp16 -> 2:4 sparsify along N (groups of 4) * scale -> wT[N][K] fp16
__global__ void __launch_bounds__(256) prep_w(const float* __restrict__ W,
                                              const float* __restrict__ scale_p,
                                              _Float16* __restrict__ wT) {
    const int tid = threadIdx.x;
    __shared__ _Float16 sT[64 * 68 + 4];   // sT[n][k], stride 68 (pad)
    const float scale = scale_p[0];
    const int k0 = (blockIdx.x & 15) * 64;
    const int n0 = (blockIdx.x >> 4) * 64;
    const int r = tid >> 4;            // 0..15
    const int c4 = (tid & 15) * 4;     // one 2:4 group = one float4
#pragma unroll
    for (int p = 0; p < 4; ++p) {
        const int k = p * 16 + r;
        float4 w4 = *(const float4*)&W[(size_t)(k0 + k) * N_TOT + n0 + c4];
        _Float16 h0 = (_Float16)w4.x, h1 = (_Float16)w4.y, h2 = (_Float16)w4.z, h3 = (_Float16)w4.w;
        float a0 = fabsf((float)h0), a1 = fabsf((float)h1), a2 = fabsf((float)h2), a3 = fabsf((float)h3);
        float lo01 = fminf(a0, a1), hi01 = fmaxf(a0, a1);
        float lo23 = fminf(a2, a3), hi23 = fmaxf(a2, a3);
        float s2 = fmaxf(fminf(hi01, hi23), fmaxf(lo01, lo23));
        sT[(c4 + 0) * 68 + k] = (_Float16)(((a0 >= s2) ? (float)h0 : 0.0f) * scale);
        sT[(c4 + 1) * 68 + k] = (_Float16)(((a1 >= s2) ? (float)h1 : 0.0f) * scale);
        sT[(c4 + 2) * 68 + k] = (_Float16)(((a2 >= s2) ? (float)h2 : 0.0f) * scale);
        sT[(c4 + 3) * 68 + k] = (_Float16)(((a3 >= s2) ? (float)h3 : 0.0f) * scale);
    }
    __syncthreads();
#pragma unroll
    for (int p = 0; p < 4; ++p) {
        const int n = p * 16 + r;
        ushort4v v = *(const ushort4v*)&sT[n * 68 + c4];
        *(ushort4v*)&wT[(size_t)(n0 + n) * K_TOT + k0 + c4] = v;
    }
}

// --- Kernel 2: r3's verified 3-buffer/1-barrier-per-phase GEMM, with A staged from
// fp32 X in-loop: plain float4 loads (compiler-managed vmcnt -- NO inline-asm regs,
// the r2 crash cause) -> v_cvt -> swizzled ds_write into the same LDS layout r3 read.
// Phase u: { A_WRITE(tile u+1 -> buf (u+1)%3)   [compiler's vmcnt wait here retires
//            last phase's A-loads AND, by issue order, B(u+1)'s gl2lds -> the
//            pre-barrier retirement invariant r3 had from manual W(4)];
//            STAGE_B(u+2 -> buf (u+2)%3); A_LOAD(u+2) [latency under this MFMA];
//            ds_read fa/fb from buf u%3; 32 MFMA;
//            s_waitcnt lgkmcnt(0); s_barrier }   [ds_writes visible; no vmcnt drain]
// WAR audit (r3 carry-over): A_WRITE target = buf read 2 barriers ago; STAGE_B
// target = buf whose reads retired 1 barrier ago; reads/writes same-phase disjoint.
__global__ void __launch_bounds__(512, 2) gemm_bt(const float* __restrict__ X,
                                                  const _Float16* __restrict__ Bt,
                                                  const float* __restrict__ bias,
                                                  float* __restrict__ C) {
    __shared__ __align__(16) _Float16 sA[3][256 * 32];   // 48 KiB
    __shared__ __align__(16) _Float16 sB[3][256 * 32];   // 48 KiB

    const int tid = threadIdx.x;
    const int id = blockIdx.x;
    const int by = id & 63;             // M tile 0..63 (by%8 = XCD; A-panel sharers co-XCD)
    const int bx = id >> 6;             // N tile 0..3
    const int wave = tid >> 6;          // 0..7
    const int lane = tid & 63;
    const int wm = wave >> 2;           // 0..1 -> M half (128 rows)
    const int wn = wave & 3;            // 0..3 -> N quarter (64 cols)
    const int quad = lane >> 4;
    const int l16 = lane & 15;

    // B staging (verbatim r3): 512 threads cover 128 rows x 64B per gl2lds
    const int row0 = tid >> 2;          // 0..127
    const int s4 = tid & 3;             // 16B slot within row
    const int g = s4 ^ ((row0 >> 1) & 3);   // pre-swizzled global k-group
    const _Float16* gB = Bt + (size_t)(bx * 256 + row0) * K_TOT + g * 8;
    const int dst0 = row0 * 32 + s4 * 8;    // LDS elem off; byte off == tid*16 (DMA-legal)

    // A staging (reg->cvt->ds_write): thread owns row ar, k-sixteenth ah (16 fp32 = 64B)
    const int ar = tid >> 1;            // 0..255
    const int ah = tid & 1;
    const float* gX = X + (size_t)(by * 256 + ar) * K_TOT + ah * 16;
    const int am = (ar >> 1) & 3;       // row swizzle phase
    const int aw0 = ar * 64 + (((2 * ah)     ^ am) << 4);   // byte offs of the two
    const int aw1 = ar * 64 + (((2 * ah + 1) ^ am) << 4);   // swizzled 16B slots
    float4 a0, a1, a2, a3;              // one A-row-slice in flight (16 VGPR)

    // ds_read side (verbatim r3): slot = quad ^ ((row>>1)&3)
    const int rdoff = l16 * 64 + ((quad ^ ((l16 >> 1) & 3)) << 4);   // bytes

    f32x4 acc[8][4];
#pragma unroll
    for (int i = 0; i < 8; ++i)
#pragma unroll
        for (int j = 0; j < 4; ++j)
            acc[i][j] = (f32x4){0.f, 0.f, 0.f, 0.f};
    f16x8 fa[8], fb[4];

#define A_LOAD(t) do {                                                     \
        const float* p_ = gX + (t) * 32;                                   \
        a0 = *(const float4*)(p_);                                         \
        a1 = *(const float4*)(p_ + 4);                                     \
        a2 = *(const float4*)(p_ + 8);                                     \
        a3 = *(const float4*)(p_ + 12);                                    \
    } while (0)
#define A_WRITE(wb) do {                                                   \
        f16x8 lo_, hi_;                                                    \
        lo_[0] = (_Float16)a0.x; lo_[1] = (_Float16)a0.y;                  \
        lo_[2] = (_Float16)a0.z; lo_[3] = (_Float16)a0.w;                  \
        lo_[4] = (_Float16)a1.x; lo_[5] = (_Float16)a1.y;                  \
        lo_[6] = (_Float16)a1.z; lo_[7] = (_Float16)a1.w;                  \
        hi_[0] = (_Float16)a2.x; hi_[1] = (_Float16)a2.y;                  \
        hi_[2] = (_Float16)a2.z; hi_[3] = (_Float16)a2.w;                  \
        hi_[4] = (_Float16)a3.x; hi_[5] = (_Float16)a3.y;                  \
        hi_[6] = (_Float16)a3.z; hi_[7] = (_Float16)a3.w;                  \
        *(f16x8*)((char*)&sA[wb][0] + aw0) = lo_;                          \
        *(f16x8*)((char*)&sA[wb][0] + aw1) = hi_;                          \
    } while (0)
#define STAGE_B(t, b) do {                                                 \
        const _Float16* sb_ = gB + (size_t)(t) * 32;                       \
        gl2lds16(sb_, &sB[b][dst0]);                                       \
        gl2lds16(sb_ + (size_t)128 * K_TOT, &sB[b][dst0 + 128 * 32]);      \
    } while (0)
#define FENCE asm volatile("" ::: "memory")

    // phase u: read buf b; optionally write A(tile u+1)->wb, stage B(t2)->b2 + load A(t2)
#define PH(b, DO_W, wb, DO_S, t2, b2) do {                                         \
        if (DO_W) A_WRITE(wb);                                                     \
        if (DO_S) { STAGE_B(t2, b2); A_LOAD(t2); }                                 \
        {                                                                          \
            const char* bA_ = (const char*)&sA[b][0] + rdoff + wm * 8192;          \
            const char* bB_ = (const char*)&sB[b][0] + rdoff + wn * 4096;          \
            _Pragma("unroll")                                                      \
            for (int j = 0; j < 4; ++j) fb[j] = *(const f16x8*)(bB_ + j * 1024);   \
            _Pragma("unroll")                                                      \
            for (int i = 0; i < 8; ++i) fa[i] = *(const f16x8*)(bA_ + i * 1024);   \
        }                                                                          \
        __builtin_amdgcn_s_setprio(1);                                             \
        _Pragma("unroll")                                                          \
        for (int i = 0; i < 8; ++i) {                                              \
            _Pragma("unroll")                                                      \
            for (int j = 0; j < 4; ++j)                                            \
                acc[i][j] = __builtin_amdgcn_mfma_f32_16x16x32_f16(                \
                    fa[i], fb[j], acc[i][j], 0, 0, 0);                             \
        }                                                                          \
        __builtin_amdgcn_s_setprio(0);                                             \
        asm volatile("s_waitcnt lgkmcnt(0)" ::: "memory");                         \
        __builtin_amdgcn_s_barrier();                                              \
        FENCE;                                                                     \
    } while (0)

    // prologue: A(0) regs -> LDS; B(0),B(1) in flight; A(1) in regs; barrier.
    A_LOAD(0);
    STAGE_B(0, 0); STAGE_B(1, 1);
    A_WRITE(0);                 // compiler waits A(0) loads (vmcnt<=4; B stays in flight)
    A_LOAD(1);
    asm volatile("s_waitcnt lgkmcnt(0)" ::: "memory");
    __builtin_amdgcn_s_barrier();
    FENCE;

    // phases 0..29: read tile u (buf u%3); write A(u+1)->buf (u+1)%3;
    // stage B(u+2)->buf (u+2)%3 + load A(u+2)
    for (int it = 0; it < 10; ++it) {
        const int t = 3 * it;
        PH(0, 1, 1, 1, t + 2, 2);
        PH(1, 1, 2, 1, t + 3, 0);
        PH(2, 1, 0, 1, t + 4, 1);
    }
    PH(0, 1, 1, 0, 0, 0);   // phase 30: read tile 30, write A(31)->buf1
    PH(1, 0, 0, 0, 0, 0);   // phase 31: read tile 31

    // epilogue (verbatim r3): D row = quad*4 + r (M), col = l16 (N); bias add
#pragma unroll
    for (int j = 0; j < 4; ++j) {
        const int col = bx * 256 + wn * 64 + j * 16 + l16;
        const float bj = bias[col];
#pragma unroll
        for (int mi = 0; mi < 8; ++mi) {
            const int row0o = by * 256 + wm * 128 + mi * 16 + quad * 4;
#pragma unroll
            for (int r = 0; r < 4; ++r) {
                C[(size_t)(row0o + r) * N_TOT + col] = acc[mi][j][r] + bj;
            }
        }
    }

#undef PH
#undef FENCE
#undef STAGE_B
#undef A_WRITE
#undef A_LOAD
}

extern "C" void kernel_launch(void* const* d_in, const int* in_sizes, int n_in,
                              void* d_out, int out_size, void* d_ws, size_t ws_size,
                              hipStream_t stream) {
    const float* x      = (const float*)d_in[0];   // [4,4096,1024] fp32
    const float* weight = (const float*)d_in[1];   // [1024,1024] fp32
    const float* bias   = (const float*)d_in[2];   // [1024] fp32
    const float* sscale = (const float*)d_in[3];   // [1] fp32
    float* out = (float*)d_out;

    _Float16* wT = (_Float16*)d_ws;                // 2 MiB

    prep_w<<<256, 256, 0, stream>>>(weight, sscale, wT);
    gemm_bt<<<256, 512, 0, stream>>>(x, wT, bias, out);
}

// Round 8
// 157.268 us; speedup vs baseline: 1.0706x; 1.0706x over previous
//
#include <hip/hip_runtime.h>
#include <hip/hip_fp16.h>
#include <stdint.h>

// out[16384,1024] = fp16(x) @ (fp16(sparsify24(fp16(W))) * scale -> fp16) + bias
#define M_TOT 16384
#define N_TOT 1024
#define K_TOT 1024

typedef _Float16 f16x8 __attribute__((ext_vector_type(8)));
typedef float f32x4 __attribute__((ext_vector_type(4)));
typedef unsigned short ushort4v __attribute__((ext_vector_type(4)));

// async global->LDS DMA, 16B per lane. LDS dest must be wave-uniform base + lane*16.
__device__ inline void gl2lds16(const void* g, void* l) {
    __builtin_amdgcn_global_load_lds(
        (const __attribute__((address_space(1))) void*)(uintptr_t)(g),
        (__attribute__((address_space(3))) void*)(uint32_t)(uintptr_t)(l),
        16, 0, 0);
}

// --- Kernel 1 (fused, verified r0/r1/r3/r6): blocks [0,256) weight prep; rest cast x.
__global__ void __launch_bounds__(256) prep_and_cast(const float* __restrict__ X,
                                                     const float* __restrict__ W,
                                                     const float* __restrict__ scale_p,
                                                     _Float16* __restrict__ Xh,
                                                     _Float16* __restrict__ wT) {
    const int tid = threadIdx.x;
    if (blockIdx.x < 256) {
        // W[K][N] fp32 -> fp16 -> 2:4 sparsify along N (groups of 4) * scale -> wT[N][K]
        __shared__ _Float16 sT[64 * 68 + 4];   // sT[n][k], stride 68 (pad)
        const float scale = scale_p[0];
        const int k0 = (blockIdx.x & 15) * 64;
        const int n0 = (blockIdx.x >> 4) * 64;
        const int r = tid >> 4;            // 0..15
        const int c4 = (tid & 15) * 4;     // one 2:4 group = one float4
#pragma unroll
        for (int p = 0; p < 4; ++p) {
            const int k = p * 16 + r;
            float4 w4 = *(const float4*)&W[(size_t)(k0 + k) * N_TOT + n0 + c4];
            _Float16 h0 = (_Float16)w4.x, h1 = (_Float16)w4.y, h2 = (_Float16)w4.z, h3 = (_Float16)w4.w;
            float a0 = fabsf((float)h0), a1 = fabsf((float)h1), a2 = fabsf((float)h2), a3 = fabsf((float)h3);
            float lo01 = fminf(a0, a1), hi01 = fmaxf(a0, a1);
            float lo23 = fminf(a2, a3), hi23 = fmaxf(a2, a3);
            float s2 = fmaxf(fminf(hi01, hi23), fmaxf(lo01, lo23));
            sT[(c4 + 0) * 68 + k] = (_Float16)(((a0 >= s2) ? (float)h0 : 0.0f) * scale);
            sT[(c4 + 1) * 68 + k] = (_Float16)(((a1 >= s2) ? (float)h1 : 0.0f) * scale);
            sT[(c4 + 2) * 68 + k] = (_Float16)(((a2 >= s2) ? (float)h2 : 0.0f) * scale);
            sT[(c4 + 3) * 68 + k] = (_Float16)(((a3 >= s2) ? (float)h3 : 0.0f) * scale);
        }
        __syncthreads();
#pragma unroll
        for (int p = 0; p < 4; ++p) {
            const int n = p * 16 + r;
            ushort4v v = *(const ushort4v*)&sT[n * 68 + c4];
            *(ushort4v*)&wT[(size_t)(n0 + n) * K_TOT + k0 + c4] = v;
        }
    } else {
        size_t i = ((size_t)(blockIdx.x - 256) * 256 + tid) * 8;
        float4 x0 = *(const float4*)&X[i];
        float4 x1 = *(const float4*)&X[i + 4];
        f16x8 h;
        h[0] = (_Float16)x0.x; h[1] = (_Float16)x0.y; h[2] = (_Float16)x0.z; h[3] = (_Float16)x0.w;
        h[4] = (_Float16)x1.x; h[5] = (_Float16)x1.y; h[6] = (_Float16)x1.z; h[7] = (_Float16)x1.w;
        *(f16x8*)&Xh[i] = h;
    }
}

// --- Kernel 2: 256x128 tile, 512 blocks = 2 blocks/CU (16 waves/CU), BK=32,
// 3-buffer depth-2 prefetch, ONE barrier/phase, counted vmcnt(3) (never drained
// to 0 mid-loop). The untried cell of the design space: r0 had 16 waves/CU but
// full vmcnt(0) drains per __syncthreads (the m97 ~20% stall); r3 had counted
// vmcnt but only 8 waves/CU. This has both levers. No sched_barrier(0)/setprio
// (m141/m190: null-to-negative here). LDS 72 KiB/block -> 144/CU (<=160 pool).
// Staging swizzle verbatim r3; fragment/epilogue formulas verbatim r0; ascending
// K order (numerics identical -> absmax 0.0078125).
__global__ void __launch_bounds__(512, 4) gemm_bt(const _Float16* __restrict__ A,
                                                  const _Float16* __restrict__ Bt,
                                                  const float* __restrict__ bias,
                                                  float* __restrict__ C) {
    __shared__ __align__(16) _Float16 sA[3][256 * 32];   // 48 KiB
    __shared__ __align__(16) _Float16 sB[3][128 * 32];   // 24 KiB

    const int tid = threadIdx.x;
    const int id = blockIdx.x;
    const int by = id & 63;             // M tile 0..63; xcd = id%8 = by%8 -> A-sharers co-XCD
    const int bx = id >> 6;             // N tile 0..7
    const int wave = tid >> 6;          // 0..7
    const int lane = tid & 63;
    const int wm = wave >> 1;           // 0..3 -> M quarter (64 rows)
    const int wn = wave & 1;            // 0..1 -> N half (64 cols)
    const int quad = lane >> 4;
    const int l16 = lane & 15;

    // staging (r3 swizzle): 512 threads cover 128 rows x 64B per gl2lds
    const int row0 = tid >> 2;          // 0..127
    const int s4 = tid & 3;             // 16B slot within row
    const int g = s4 ^ ((row0 >> 1) & 3);   // pre-swizzled global k-group
    const _Float16* gA = A + (size_t)(by * 256 + row0) * K_TOT + g * 8;
    const _Float16* gB = Bt + (size_t)(bx * 128 + row0) * K_TOT + g * 8;
    const int dst0 = row0 * 32 + s4 * 8;    // LDS elem off; byte off == tid*16 (DMA-legal)

    // ds_read side (r3): slot = quad ^ ((row>>1)&3); row ≡ l16 mod 16 -> lane-const
    const int rdoff = l16 * 64 + ((quad ^ ((l16 >> 1) & 3)) << 4);   // bytes

    f32x4 acc[4][4];
#pragma unroll
    for (int i = 0; i < 4; ++i)
#pragma unroll
        for (int j = 0; j < 4; ++j)
            acc[i][j] = (f32x4){0.f, 0.f, 0.f, 0.f};
    f16x8 fa[4], fb[4];

#define STAGE(t, b) do {                                                   \
        const _Float16* sa_ = gA + (size_t)(t) * 32;                       \
        gl2lds16(sa_, &sA[b][dst0]);                                       \
        gl2lds16(sa_ + (size_t)128 * K_TOT, &sA[b][dst0 + 128 * 32]);      \
        const _Float16* sb_ = gB + (size_t)(t) * 32;                       \
        gl2lds16(sb_, &sB[b][dst0]);                                       \
    } while (0)
#define FENCE asm volatile("" ::: "memory")

    // phase u: wait tile u's 3 loads; barrier; stage tile u+2 -> buf (u+2)%3;
    // ds_read; 16 MFMA. Race audit = r3: stage target buf((u+2)%3)==buf((u-1)%3),
    // whose ds_reads retired before this barrier; DMA writes land before the
    // issuing wave's phase-(u+2) vmcnt, hence before the barrier readers cross.
#define PH(b, t2, b2, DO_STAGE, WLAST) do {                                        \
        if (WLAST) asm volatile("s_waitcnt vmcnt(0)" ::: "memory");                \
        else       asm volatile("s_waitcnt vmcnt(3)" ::: "memory");                \
        __builtin_amdgcn_s_barrier();                                              \
        FENCE;                                                                     \
        if (DO_STAGE) STAGE(t2, b2);                                               \
        {                                                                          \
            const char* bA_ = (const char*)&sA[b][0] + rdoff + wm * 4096;          \
            const char* bB_ = (const char*)&sB[b][0] + rdoff + wn * 4096;          \
            _Pragma("unroll")                                                      \
            for (int j = 0; j < 4; ++j) fb[j] = *(const f16x8*)(bB_ + j * 1024);   \
            _Pragma("unroll")                                                      \
            for (int i = 0; i < 4; ++i) fa[i] = *(const f16x8*)(bA_ + i * 1024);   \
        }                                                                          \
        _Pragma("unroll")                                                          \
        for (int i = 0; i < 4; ++i) {                                              \
            _Pragma("unroll")                                                      \
            for (int j = 0; j < 4; ++j)                                            \
                acc[i][j] = __builtin_amdgcn_mfma_f32_16x16x32_f16(                \
                    fa[i], fb[j], acc[i][j], 0, 0, 0);                             \
        }                                                                          \
    } while (0)

    // prologue: tiles 0 and 1 in flight (6 loads)
    STAGE(0, 0);
    STAGE(1, 1);

    // phases 0..29: read tile u from buf u%3, stage tile u+2 into buf (u+2)%3
    for (int it = 0; it < 10; ++it) {
        const int t = 3 * it;
        PH(0, t + 2, 2, 1, 0);
        PH(1, t + 3, 0, 1, 0);
        PH(2, t + 4, 1, 1, 0);
    }
    PH(0, 0, 0, 0, 0);   // phase 30: tile 30, no stage, vmcnt(3) retires tile 30
    PH(1, 0, 0, 0, 1);   // phase 31: tile 31, no stage, vmcnt(0)

    // epilogue (verbatim r0): D row = quad*4 + r (M), col = l16 (N); bias add
#pragma unroll
    for (int j = 0; j < 4; ++j) {
        const int col = bx * 128 + wn * 64 + j * 16 + l16;
        const float bj = bias[col];
#pragma unroll
        for (int i = 0; i < 4; ++i) {
            const int row0o = by * 256 + wm * 64 + i * 16 + quad * 4;
#pragma unroll
            for (int r = 0; r < 4; ++r) {
                C[(size_t)(row0o + r) * N_TOT + col] = acc[i][j][r] + bj;
            }
        }
    }

#undef PH
#undef FENCE
#undef STAGE
}

extern "C" void kernel_launch(void* const* d_in, const int* in_sizes, int n_in,
                              void* d_out, int out_size, void* d_ws, size_t ws_size,
                              hipStream_t stream) {
    const float* x      = (const float*)d_in[0];   // [4,4096,1024] fp32
    const float* weight = (const float*)d_in[1];   // [1024,1024] fp32
    const float* bias   = (const float*)d_in[2];   // [1024] fp32
    const float* sscale = (const float*)d_in[3];   // [1] fp32
    float* out = (float*)d_out;

    _Float16* wT = (_Float16*)d_ws;                                    // 2 MiB
    _Float16* xh = (_Float16*)((char*)d_ws + (size_t)2 * 1024 * 1024); // 32 MiB

    prep_and_cast<<<256 + (M_TOT * K_TOT / 8) / 256, 256, 0, stream>>>(x, weight, sscale, xh, wT);
    gemm_bt<<<512, 512, 0, stream>>>(xh, wT, bias, out);
}